// Round 1
// baseline (3295.481 us; speedup 1.0000x reference)
//
#include <hip/hip_runtime.h>

typedef unsigned short ushort;
typedef unsigned int uint;
typedef __bf16 bf16x8 __attribute__((ext_vector_type(8)));
typedef ushort ushort8 __attribute__((ext_vector_type(8)));
typedef float f32x4 __attribute__((ext_vector_type(4)));

#define Z4 f32x4{0.f, 0.f, 0.f, 0.f}

__device__ __forceinline__ f32x4 mfma16(bf16x8 a, bf16x8 b, f32x4 c) {
    return __builtin_amdgcn_mfma_f32_16x16x32_bf16(a, b, c, 0, 0, 0);
}
__device__ __forceinline__ float bf2f(ushort h) {
    union { uint u; float f; } v; v.u = ((uint)h) << 16; return v.f;
}
__device__ __forceinline__ ushort f2bf(float f) {  // RNE
    union { float f; uint u; } v; v.f = f;
    uint u = v.u;
    uint r = (u + 0x7fffu + ((u >> 16) & 1u)) >> 16;
    return (ushort)r;
}
__device__ __forceinline__ float sigmoidf_(float x) { return 1.f / (1.f + __expf(-x)); }
__device__ __forceinline__ float tanhf_(float x) {
    float e = __expf(2.f * x);
    return 1.f - 2.f / (e + 1.f);
}

typedef __attribute__((address_space(1))) uint guint;
typedef __attribute__((address_space(3))) uint luint;
__device__ __forceinline__ void dma16(const ushort* g, ushort* l) {
    __builtin_amdgcn_global_load_lds((const guint*)g, (luint*)l, 16, 0, 0);
}
template <int N> __device__ __forceinline__ void ring_wait() {
    asm volatile("s_waitcnt vmcnt(%0)" ::"n"(N) : "memory");
}
// raw barrier: LDS ordering only — does NOT drain the per-wave DMA ring (vmcnt)
__device__ __forceinline__ void wg_sync() {
    asm volatile("s_waitcnt lgkmcnt(0)\n\ts_barrier" ::: "memory");
}

// ---------------------------------------------------------------------------
// Weight pre-pack, MFMA-B fragment-major: frag F = ntile*(K/32)+kf, 1 KB each.
// ---------------------------------------------------------------------------
__global__ void pack_direct_k(const float* __restrict__ src, ushort* __restrict__ dst,
                              int N, int K) {  // src row-major [N,K]
    int total = (N >> 4) * (K >> 5) * 64;
    int idx = blockIdx.x * 256 + threadIdx.x;
    if (idx >= total) return;
    int l = idx & 63, f = idx >> 6;
    int kfrags = K >> 5;
    int nt = f / kfrags, kf = f - nt * kfrags;
    int n = nt * 16 + (l & 15);
    int k0 = kf * 32 + (l >> 4) * 8;
    const float* s = src + (size_t)n * K + k0;
    ushort8 u;
#pragma unroll
    for (int j = 0; j < 8; j++) u[j] = f2bf(s[j]);
    *(ushort8*)&dst[(size_t)f * 512 + l * 8] = u;
}
__global__ void pack_trans_k(const float* __restrict__ src, ushort* __restrict__ dst,
                             int N, int K) {  // src row-major [K,N]
    int total = (N >> 4) * (K >> 5) * 64;
    int idx = blockIdx.x * 256 + threadIdx.x;
    if (idx >= total) return;
    int l = idx & 63, f = idx >> 6;
    int kfrags = K >> 5;
    int nt = f / kfrags, kf = f - nt * kfrags;
    int n = nt * 16 + (l & 15);
    int k0 = kf * 32 + (l >> 4) * 8;
    ushort8 u;
#pragma unroll
    for (int j = 0; j < 8; j++) u[j] = f2bf(src[(size_t)(k0 + j) * N + n]);
    *(ushort8*)&dst[(size_t)f * 512 + l * 8] = u;
}

// ---------------------------------------------------------------------------
// Fused MLP: X2 = relu(H@W1+b1)@W2+b2  -> bf16 [65536,256]
// 1024 blocks x 256 thr (4 waves); 64 rows/block; packed-B frags from global.
// ---------------------------------------------------------------------------
__global__ __launch_bounds__(256) void mlp_kernel(
    const float* __restrict__ H,     // [65536,128] fp32
    const ushort* __restrict__ W1P,  // packed N=512,K=128
    const float* __restrict__ b1,
    const ushort* __restrict__ W2P,  // packed N=256,K=512
    const float* __restrict__ b2,
    ushort* __restrict__ X2)         // [65536,256] bf16
{
    __shared__ __align__(16) ushort sH[64][136];
    __shared__ __align__(16) ushort sT[64][264];
    __shared__ float sb1[512], sb2[256];
    const int tid = threadIdx.x;
    const int w = tid >> 6, lane = tid & 63;
    const int q = lane >> 4, tc = lane & 15;
    const int lo8 = lane * 8;
    const int m0 = blockIdx.x * 64;

    {   // stage H 64x128 fp32 -> bf16
        int r = tid >> 2, c0 = (tid & 3) * 32;
        const float* src = H + (size_t)(m0 + r) * 128 + c0;
#pragma unroll
        for (int v = 0; v < 4; v++) {
            float4 a = *(const float4*)(src + v * 8);
            float4 b = *(const float4*)(src + v * 8 + 4);
            ushort8 u;
            u[0] = f2bf(a.x); u[1] = f2bf(a.y); u[2] = f2bf(a.z); u[3] = f2bf(a.w);
            u[4] = f2bf(b.x); u[5] = f2bf(b.y); u[6] = f2bf(b.z); u[7] = f2bf(b.w);
            *(ushort8*)&sH[r][c0 + v * 8] = u;
        }
    }
    for (int i = tid; i < 512; i += 256) sb1[i] = b1[i];
    if (tid < 256) sb2[tid] = b2[tid];
    __syncthreads();

    bf16x8 af[4];
#pragma unroll
    for (int kb = 0; kb < 4; kb++) af[kb] = *(const bf16x8*)&sH[w * 16 + tc][kb * 32 + q * 8];

    f32x4 accH[16];
#pragma unroll
    for (int nt = 0; nt < 16; nt++) accH[nt] = Z4;

#pragma unroll 1
    for (int half = 0; half < 2; half++) {
        __syncthreads();  // protect sT reuse across halves
#pragma unroll
        for (int j = 0; j < 16; j++) {
            int n = half * 256 + j * 16 + tc;
            const ushort* bp = W1P + (size_t)((half * 16 + j) * 4) * 512 + lo8;
            f32x4 a = Z4;
#pragma unroll
            for (int kb = 0; kb < 4; kb++)
                a = mfma16(af[kb], *(const bf16x8*)(bp + kb * 512), a);
            float bv = sb1[n];
#pragma unroll
            for (int i = 0; i < 4; i++)
                sT[w * 16 + q * 4 + i][j * 16 + tc] = f2bf(fmaxf(a[i] + bv, 0.f));
        }
        __syncthreads();

        bf16x8 a2[8];
#pragma unroll
        for (int kb = 0; kb < 8; kb++) a2[kb] = *(const bf16x8*)&sT[w * 16 + tc][kb * 32 + q * 8];
#pragma unroll
        for (int nt = 0; nt < 16; nt++) {
            const ushort* bp = W2P + (size_t)(nt * 16 + half * 8) * 512 + lo8;
#pragma unroll
            for (int kb = 0; kb < 8; kb++)
                accH[nt] = mfma16(a2[kb], *(const bf16x8*)(bp + kb * 512), accH[nt]);
        }
    }

#pragma unroll
    for (int nt = 0; nt < 16; nt++) {
        int col = nt * 16 + tc;
        float bv = sb2[col];
#pragma unroll
        for (int i = 0; i < 4; i++)
            X2[(size_t)(m0 + w * 16 + q * 4 + i) * 256 + col] = f2bf(accH[nt][i] + bv);
    }
}

// ---------------------------------------------------------------------------
// GEMM, packed-B: C = A @ B^T + bias.  A bf16 row-major [M,K], BP packed.
// mode 0: bf16 row-major out; 1: fp32 row-major out; 2: bf16 Xg-swizzle out
//   (swizzle: row=b*128+t -> dst[((b>>4)*128+t)*N + col]*16 + (b&15))
// ---------------------------------------------------------------------------
__global__ __launch_bounds__(256) void gemm128P(
    const ushort* __restrict__ A, const ushort* __restrict__ BP,
    const float* __restrict__ bias, void* __restrict__ Cout,
    int M, int N, int K, int mode)
{
    __shared__ __align__(16) ushort sA[128][40];
    const int tid = threadIdx.x;
    const int lane = tid & 63, wid = tid >> 6;
    const int q = lane >> 4, tc = lane & 15;
    const int lo8 = lane * 8;
    const int wm = (wid >> 1) * 64, wn = (wid & 1) * 64;
    const int bm = blockIdx.y * 128, bn = blockIdx.x * 128;

    f32x4 acc[4][4];
#pragma unroll
    for (int im = 0; im < 4; im++)
#pragma unroll
        for (int in_ = 0; in_ < 4; in_++) acc[im][in_] = Z4;

    const int arow = tid >> 1, acol = (tid & 1) * 16;
    const int kfrags = K >> 5;

    for (int kc = 0; kc < K; kc += 32) {
        const ushort* ga = A + (size_t)(bm + arow) * K + kc + acol;
        ushort8 va0 = *(const ushort8*)ga;
        ushort8 va1 = *(const ushort8*)(ga + 8);
        __syncthreads();
        *(ushort8*)&sA[arow][acol] = va0;
        *(ushort8*)&sA[arow][acol + 8] = va1;
        __syncthreads();

        bf16x8 af[4], bf[4];
#pragma unroll
        for (int im = 0; im < 4; im++) af[im] = *(const bf16x8*)&sA[wm + im * 16 + tc][q * 8];
#pragma unroll
        for (int in_ = 0; in_ < 4; in_++) {
            int nt = ((bn + wn) >> 4) + in_;
            bf[in_] = *(const bf16x8*)(BP + (size_t)(nt * kfrags + (kc >> 5)) * 512 + lo8);
        }
#pragma unroll
        for (int im = 0; im < 4; im++)
#pragma unroll
            for (int in_ = 0; in_ < 4; in_++)
                acc[im][in_] = mfma16(af[im], bf[in_], acc[im][in_]);
    }

#pragma unroll
    for (int in_ = 0; in_ < 4; in_++) {
        int col = bn + wn + in_ * 16 + tc;
        float bv = bias[col];
#pragma unroll
        for (int im = 0; im < 4; im++) {
            int row0 = bm + wm + im * 16 + q * 4;
#pragma unroll
            for (int r = 0; r < 4; r++) {
                float v = acc[im][in_][r] + bv;
                int row = row0 + r;
                if (mode == 0) {
                    ((ushort*)Cout)[(size_t)row * N + col] = f2bf(v);
                } else if (mode == 1) {
                    ((float*)Cout)[(size_t)row * N + col] = v;
                } else {
                    int b = row >> 7, t = row & 127;
                    size_t dst = (((size_t)(b >> 4) * 128 + t) * N + col) * 16 + (b & 15);
                    ((ushort*)Cout)[dst] = f2bf(v);
                }
            }
        }
    }
}

// ---------------------------------------------------------------------------
// Slim sequential scan.  v2 ring schedule:
//   ring[8][4][2048] (128 KB): per-wave 4 slots x 4 KB.
//   Ohh (16 KB/wave) is loaded ONCE per step into slots 0..3, issued at the
//   TAIL of the previous step (covered by epilogue+barrier+phase1); substeps
//   read it from LDS with no vmcnt waits (one drain at substep 1).
//   Whh (48 KB/wave) streams through the same slots: W0..W3 issued during
//   substep 4 (after each Ohh chunk's last read), W4..W11 pumped 4-deep
//   through the GRU chunks with counted vmcnt (never drained early).
// Per-step streamed bytes: 896 KB -> 512 KB per WG; substep-interior vmcnt
// waits: 16 -> 1.
// Per-step vmem issue order (per wave), which the counted waits rely on:
//   A0..A3 (16, prev tail) | hseq store (1, prev tail) | xg (6, step start)
//   | W0..W3 (16, substep 4) | W4..W11 (pumped in GRU chunks 0..7)
// ---------------------------------------------------------------------------
__global__ __launch_bounds__(512, 2) void scan_fused(
    const ushort* __restrict__ XgSw,  // [32][128][768][16] bf16 swizzled
    const ushort* __restrict__ OhrP, const ushort* __restrict__ OhzP,
    const ushort* __restrict__ OhhP,  // packed N=256,K=256
    const ushort* __restrict__ WhhP,  // packed N=768,K=256
    const float*  __restrict__ bhh,   // [768]
    ushort* __restrict__ hseq)        // [65536,256] bf16, row = b*128+t
{
    const int m0 = blockIdx.x * 16;
    const int tid = threadIdx.x;
    const int w = tid >> 6, lane = tid & 63;
    const int q = lane >> 4, tc = lane & 15;
    const int lo8 = lane * 8;

    __shared__ __align__(16) ushort ring[8][4][2048];  // 128 KB
    __shared__ __align__(16) ushort h_bf[16][264];
    __shared__ __align__(16) ushort rh_bf[16][264];

    for (int i = tid; i < 16 * 264; i += 512) (&h_bf[0][0])[i] = 0;

    const int colbase = w * 32 + tc;
    const int cA = colbase, cB = colbase + 16;

    // biases (x-side bih already folded into Xg)
    float rbv[2]  = { bhh[cA], bhh[cB] };
    float zbv[2]  = { bhh[256 + cA], bhh[256 + cB] };
    float hnbv[2] = { bhh[512 + cA], bhh[512 + cB] };

    // persistent ODE r/z weights (2 ntiles x 8 kf each = 128 VGPRs)
    bf16x8 wOr[16], wOz[16];
#pragma unroll
    for (int f = 0; f < 16; f++) {
        wOr[f] = *(const bf16x8*)(OhrP + (size_t)(w * 16 + f) * 512 + lo8);
        wOz[f] = *(const bf16x8*)(OhzP + (size_t)(w * 16 + f) * 512 + lo8);
    }

    float hreg[2][4] = {{0.f, 0.f, 0.f, 0.f}, {0.f, 0.f, 0.f, 0.f}};

    // 4 KB pump into this wave's ring slot.  lgkmcnt(0) protects slot reuse
    // (all prior ds_reads of this wave must have completed).
    auto pump4k = [&](const ushort* g, int slot) {
        asm volatile("s_waitcnt lgkmcnt(0)" ::: "memory");
        g += lo8;
        ushort* sb = &ring[w][slot][0];
        dma16(g, sb); dma16(g + 512, sb + 512);
        dma16(g + 1024, sb + 1024); dma16(g + 1536, sb + 1536);
    };
    auto pumpA = [&](int c) {  // Ohh chunk c -> slot c (frags c*4..c*4+3)
        pump4k(OhhP + (size_t)(w * 16 + c * 4) * 512, c);
    };
    auto pumpW = [&](int j) {  // Whh chunk j -> slot j&3
        int b = j >> 1, half = j & 1;
        int nt = b / 3, gg = b - nt * 3;
        pump4k(WhhP + (size_t)((gg * 16 + w * 2 + nt) * 8 + half * 4) * 512, j & 3);
    };

    __syncthreads();  // h_bf zero-fill visible (full barrier OK: no DMA yet)

    // prologue Ohh load for t=0 (steady-state issues this at the step tail)
    pumpA(0); pumpA(1); pumpA(2); pumpA(3);

#pragma unroll 1
    for (int t = 0; t < 128; t++) {
        // x-gate loads (consumed at GRU epilogue; drained by GRU chunk 0 wait)
        const ushort* xgp = XgSw + (((size_t)blockIdx.x * 128 + t) * 768) * 16;
        uint2 xg[6];
#pragma unroll
        for (int g = 0; g < 3; g++)
#pragma unroll
            for (int nt = 0; nt < 2; nt++)
                xg[g * 2 + nt] =
                    *(const uint2*)(xgp + (size_t)(g * 256 + colbase + nt * 16) * 16 + q * 4);

        // ---- 4 Euler ODE substeps (Ohh resident in ring slots 0..3) ----
#pragma unroll 1
        for (int s = 0; s < 4; s++) {
            bf16x8 af[8];
#pragma unroll
            for (int k = 0; k < 8; k++) af[k] = *(const bf16x8*)&h_bf[tc][k * 32 + q * 8];
            f32x4 ar[2] = { Z4, Z4 }, az[2] = { Z4, Z4 };
#pragma unroll
            for (int nt = 0; nt < 2; nt++)
#pragma unroll
                for (int k = 0; k < 8; k++) {
                    ar[nt] = mfma16(af[k], wOr[nt * 8 + k], ar[nt]);
                    az[nt] = mfma16(af[k], wOz[nt * 8 + k], az[nt]);
                }
            float zs[2][4];
#pragma unroll
            for (int nt = 0; nt < 2; nt++)
#pragma unroll
                for (int i = 0; i < 4; i++) {
                    float rv = sigmoidf_(ar[nt][i]);
                    zs[nt][i] = sigmoidf_(az[nt][i]);
                    rh_bf[q * 4 + i][colbase + nt * 16] = f2bf(rv * hreg[nt][i]);
                }
            wg_sync();  // rh ready

            bf16x8 au[8];
#pragma unroll
            for (int k = 0; k < 8; k++) au[k] = *(const bf16x8*)&rh_bf[tc][k * 32 + q * 8];
            f32x4 uu[2] = { Z4, Z4 };
            if (s == 0) {
                // drain the step's Ohh pumps (issued last step's tail).
                // t==0: outstanding = A(16)+xg(6)           -> leave 6
                // t>=1: outstanding = A(16)+store(1)+xg(6)  -> leave 7
                if (t == 0) ring_wait<6>(); else ring_wait<7>();
            }
#pragma unroll
            for (int c = 0; c < 4; c++) {  // chunk c: nt=c>>1, k-half=c&1
                const ushort* sb = &ring[w][c][0] + lo8;
                bf16x8 v0 = *(const bf16x8*)(sb);
                bf16x8 v1 = *(const bf16x8*)(sb + 512);
                bf16x8 v2 = *(const bf16x8*)(sb + 1024);
                bf16x8 v3 = *(const bf16x8*)(sb + 1536);
                uu[c >> 1] = mfma16(au[(c & 1) * 4 + 0], v0, uu[c >> 1]);
                uu[c >> 1] = mfma16(au[(c & 1) * 4 + 1], v1, uu[c >> 1]);
                uu[c >> 1] = mfma16(au[(c & 1) * 4 + 2], v2, uu[c >> 1]);
                uu[c >> 1] = mfma16(au[(c & 1) * 4 + 3], v3, uu[c >> 1]);
                // last substep: this Ohh chunk is dead -> refill with Whh.
                // pump's lgkmcnt(0) guarantees the ds_reads above completed.
                if (s == 3) pumpW(c);
            }
#pragma unroll
            for (int nt = 0; nt < 2; nt++)
#pragma unroll
                for (int i = 0; i < 4; i++) {
                    float hv = hreg[nt][i];
                    float hn = hv + 0.25f * (1.f - zs[nt][i]) * (tanhf_(uu[nt][i]) - hv);
                    hreg[nt][i] = hn;
                    h_bf[q * 4 + i][colbase + nt * 16] = f2bf(hn);
                }
            wg_sync();  // h ready
        }

        // ---- GRU h-part: Whh, 12 chunks, 4-deep counted-vmcnt pipeline ----
        bf16x8 ah[8];
#pragma unroll
        for (int k = 0; k < 8; k++) ah[k] = *(const bf16x8*)&h_bf[tc][k * 32 + q * 8];
        f32x4 accr[2] = { Z4, Z4 }, accz[2] = { Z4, Z4 }, accn[2] = { Z4, Z4 };

        // Wait arithmetic (per wave): at chunk 0, outstanding =
        // store(<=1)+xg(6)+W0..W3(16); <12> drains store+xg+W0.  Chunks 1..8
        // see exactly {Wi..Wi+3}=16 -> <12> drains Wi.  Tail: <8>,<4>,<0>.
#define GRU_CHUNK(I, WN)                                                        \
        {                                                                       \
            constexpr int b_ = (I) >> 1, half_ = (I) & 1;                       \
            constexpr int nt_ = b_ / 3, gg_ = b_ - nt_ * 3;                     \
            ring_wait<WN>();                                                    \
            const ushort* sb = &ring[w][(I) & 3][0] + lo8;                      \
            bf16x8 v0 = *(const bf16x8*)(sb);                                   \
            bf16x8 v1 = *(const bf16x8*)(sb + 512);                             \
            bf16x8 v2 = *(const bf16x8*)(sb + 1024);                            \
            bf16x8 v3 = *(const bf16x8*)(sb + 1536);                            \
            if ((I) <= 7) pumpW((I) + 4);                                       \
            f32x4* tgt = (gg_ == 0) ? &accr[nt_] : (gg_ == 1) ? &accz[nt_]      \
                                                              : &accn[nt_];    \
            *tgt = mfma16(ah[half_ * 4 + 0], v0, *tgt);                         \
            *tgt = mfma16(ah[half_ * 4 + 1], v1, *tgt);                         \
            *tgt = mfma16(ah[half_ * 4 + 2], v2, *tgt);                         \
            *tgt = mfma16(ah[half_ * 4 + 3], v3, *tgt);                         \
        }
        GRU_CHUNK(0, 12)  GRU_CHUNK(1, 12)  GRU_CHUNK(2, 12)  GRU_CHUNK(3, 12)
        GRU_CHUNK(4, 12)  GRU_CHUNK(5, 12)  GRU_CHUNK(6, 12)  GRU_CHUNK(7, 12)
        GRU_CHUNK(8, 12)  GRU_CHUNK(9, 8)   GRU_CHUNK(10, 4)  GRU_CHUNK(11, 0)
#undef GRU_CHUNK
        wg_sync();  // all h_bf reads done

        // issue next step's Ohh now: covered by epilogue + store + barrier +
        // next phase 1.  (ring fully drained by chunk 11's <0>; lgkmcnt(0) in
        // pump covers chunk 11's ds_reads.)
        pumpA(0); pumpA(1); pumpA(2); pumpA(3);

        // ---- GRU epilogue (xg drained at GRU chunk 0's wait) ----
#pragma unroll
        for (int nt = 0; nt < 2; nt++) {
            int col = colbase + nt * 16;
#pragma unroll
            for (int i = 0; i < 4; i++) {
                uint2 ur = xg[0 + nt], uz = xg[2 + nt], un = xg[4 + nt];
                uint wr = (i < 2) ? ur.x : ur.y, wz = (i < 2) ? uz.x : uz.y,
                     wn = (i < 2) ? un.x : un.y;
                int sh = (i & 1) * 16;
                float xr = bf2f((ushort)(wr >> sh)), xz = bf2f((ushort)(wz >> sh)),
                      xn = bf2f((ushort)(wn >> sh));
                float rg = sigmoidf_(accr[nt][i] + xr + rbv[nt]);
                float zg = sigmoidf_(accz[nt][i] + xz + zbv[nt]);
                float ng = tanhf_(xn + rg * (accn[nt][i] + hnbv[nt]));
                float hv = hreg[nt][i];
                float hn = (1.f - zg) * ng + zg * hv;
                hreg[nt][i] = hn;
                h_bf[q * 4 + i][col] = f2bf(hn);
            }
        }
        wg_sync();  // h_new visible

        // ---- coalesced h store for the trailing projection GEMM ----
        {
            int row = tid >> 5, col = (tid & 31) * 8;
            ushort8 hv = *(const ushort8*)&h_bf[row][col];
            *(ushort8*)&hseq[((size_t)(m0 + row) * 128 + t) * 256 + col] = hv;
        }
    }
}

// ---------------------------------------------------------------------------
// Launch.  Workspace 129.6 MB:
//   [0, 100663296)            Xg swizzled [32][128][768][16] bf16
//   [100663296, 134217728)    X2 [65536,256] bf16  (aliased by hseq after use)
//   [134217728, ...)          packed weights (1.44 MB)
// ---------------------------------------------------------------------------
extern "C" void kernel_launch(void* const* d_in, const int* in_sizes, int n_in,
                              void* d_out, int out_size, void* d_ws, size_t ws_size,
                              hipStream_t stream) {
    const float* H   = (const float*)d_in[0];
    const float* W1  = (const float*)d_in[2];
    const float* b1  = (const float*)d_in[3];
    const float* W2  = (const float*)d_in[4];
    const float* b2  = (const float*)d_in[5];
    const float* Ohr = (const float*)d_in[6];
    const float* Ohz = (const float*)d_in[7];
    const float* Ohh = (const float*)d_in[8];
    const float* Wih = (const float*)d_in[9];
    const float* Whh = (const float*)d_in[10];
    const float* bih = (const float*)d_in[11];
    const float* bhh = (const float*)d_in[12];
    const float* Wr  = (const float*)d_in[13];
    const float* br  = (const float*)d_in[14];
    float* out = (float*)d_out;
    char* ws = (char*)d_ws;

    ushort* Xg   = (ushort*)(ws);
    ushort* X2   = (ushort*)(ws + 100663296);
    ushort* hseq = X2;  // alias: X2 dead before scan writes hseq
    char* pk = ws + 134217728;
    ushort* W1P  = (ushort*)(pk);
    ushort* W2P  = (ushort*)(pk + 131072);
    ushort* WrP  = (ushort*)(pk + 393216);
    ushort* OhrP = (ushort*)(pk + 458752);
    ushort* OhzP = (ushort*)(pk + 589824);
    ushort* OhhP = (ushort*)(pk + 720896);
    ushort* WihP = (ushort*)(pk + 851968);
    // end at +1245184

    pack_trans_k<<<dim3(32),  256, 0, stream>>>(W1,  W1P, 512, 128);
    pack_trans_k<<<dim3(64),  256, 0, stream>>>(W2,  W2P, 256, 512);
    pack_trans_k<<<dim3(16),  256, 0, stream>>>(Wr,  WrP, 128, 256);
    pack_direct_k<<<dim3(32), 256, 0, stream>>>(Ohr, OhrP, 256, 256);
    pack_direct_k<<<dim3(32), 256, 0, stream>>>(Ohz, OhzP, 256, 256);
    pack_direct_k<<<dim3(32), 256, 0, stream>>>(Ohh, OhhP, 256, 256);
    pack_direct_k<<<dim3(96), 256, 0, stream>>>(Wih, WihP, 768, 256);
    pack_direct_k<<<dim3(96), 256, 0, stream>>>(Whh, (ushort*)(pk + 1245184), 768, 256);
    ushort* WhhP = (ushort*)(pk + 1245184);

    // Phase A: X2 = MLP(H); Xg = X2 @ Wih^T + bih (swizzled for the scan)
    mlp_kernel<<<dim3(1024), 256, 0, stream>>>(H, W1P, b1, W2P, b2, X2);
    gemm128P<<<dim3(6, 512), 256, 0, stream>>>(X2, WihP, bih, Xg, 65536, 768, 256, 2);

    // Phase B: sequential scan -> hseq (aliases X2; X2 fully consumed above)
    scan_fused<<<dim3(32), 512, 0, stream>>>(Xg, OhrP, OhzP, OhhP, WhhP, bhh, hseq);

    // Phase C: out = hseq @ Wr + br (fp32)
    gemm128P<<<dim3(1, 512), 256, 0, stream>>>(hseq, WrP, br, out, 65536, 128, 256, 1);
}